// Round 8
// baseline (487.946 us; speedup 1.0000x reference)
//
#include <hip/hip_runtime.h>
#include <hip/hip_bf16.h>

#define DIM 384
#define SEQ 3136   // 56*56
#define NBATCH 8

typedef __attribute__((ext_vector_type(8))) short short8;  // 8 x bf16 (4 VGPRs)
typedef __attribute__((ext_vector_type(4))) float fx4;
typedef __attribute__((ext_vector_type(4))) int i4;
typedef __hip_bfloat16 bf16;

#define MFMA(a,b,c) __builtin_amdgcn_mfma_f32_16x16x32_bf16(a,b,c,0,0,0)

// -------- x[b][c][n] f32 -> kb[b][n][c] bf16 (transpose + convert) --------
__global__ __launch_bounds__(256) void ktrans(const float* __restrict__ x,
                                              bf16* __restrict__ kb) {
  __shared__ float t[64][65];
  int b = blockIdx.z;
  int n0 = blockIdx.x * 64, c0 = blockIdx.y * 64;
  int tid = threadIdx.x;
  {
    int nl = tid & 63, cl = tid >> 6;
    const float* xp = x + ((size_t)b * DIM + c0) * SEQ + n0;
    #pragma unroll
    for (int p = 0; p < 16; ++p) {
      int c = cl * 16 + p;
      t[c][nl] = xp[(size_t)c * SEQ + nl];
    }
  }
  __syncthreads();
  {
    int cc = tid & 63, nr = tid >> 6;
    bf16* kp = kb + ((size_t)b * SEQ + n0) * DIM + c0;
    #pragma unroll
    for (int p = 0; p < 16; ++p) {
      int n = nr * 16 + p;
      kp[(size_t)n * DIM + cc] = __float2bfloat16(t[cc][n]);
    }
  }
}

// -------- weights f32 -> bf16 --------
__global__ __launch_bounds__(256) void kwconv(const float* __restrict__ w1,
                                              const float* __restrict__ w2,
                                              bf16* __restrict__ w1b,
                                              bf16* __restrict__ w2b) {
  int i = blockIdx.x * 256 + threadIdx.x;   // grid covers DIM*DIM exactly
  w1b[i] = __float2bfloat16(w1[i]);
  w2b[i] = __float2bfloat16(w2[i]);
}

// -------- out[r][c] = sum_k A[r][k] * Bt[c][k]   (both K-contiguous, K=384) --------
// K split into two 192-wide staged steps: LDS 51,200 B -> 3 blocks/CU
// (R7-proven: banked ~26 us vs the 1-block/CU full-K version).
__global__ __launch_bounds__(256, 3) void kgemm(const bf16* __restrict__ A, long long Abs,
                                                const bf16* __restrict__ Bt, long long Bbs,
                                                bf16* __restrict__ out, long long Obs, int ldo) {
  __shared__ __align__(16) bf16 At[64][200];
  __shared__ __align__(16) bf16 Bs[64][200];
  int b = blockIdx.z;
  int tid = threadIdx.x;
  const bf16* Ab = A + (size_t)b * Abs + (size_t)blockIdx.x * 64 * DIM;
  const bf16* Bb = Bt + (size_t)b * Bbs + (size_t)blockIdx.y * 64 * DIM;
  int row = tid >> 2, cb = (tid & 3) * 48;
  int wave = tid >> 6, lane = tid & 63;
  int r = lane & 15, kq = lane >> 4;
  fx4 zero = {0.f, 0.f, 0.f, 0.f};
  fx4 acc[4];
  #pragma unroll
  for (int i = 0; i < 4; ++i) acc[i] = zero;
  #pragma unroll
  for (int kb = 0; kb < DIM; kb += 192) {
    if (kb) __syncthreads();   // all waves done reading previous K-step tiles
    {
      const i4* ga = (const i4*)(Ab + (size_t)row * DIM + kb + cb);
      const i4* gb = (const i4*)(Bb + (size_t)row * DIM + kb + cb);
      i4* la = (i4*)(&At[row][cb]);
      i4* lb = (i4*)(&Bs[row][cb]);
      #pragma unroll
      for (int p = 0; p < 6; ++p) { la[p] = ga[p]; lb[p] = gb[p]; }
    }
    __syncthreads();
    #pragma unroll
    for (int ks = 0; ks < 6; ++ks) {
      short8 af = *(const short8*)(&At[wave * 16 + r][ks * 32 + kq * 8]);
      #pragma unroll
      for (int ct = 0; ct < 4; ++ct) {
        short8 bfr = *(const short8*)(&Bs[ct * 16 + r][ks * 32 + kq * 8]);
        acc[ct] = MFMA(af, bfr, acc[ct]);
      }
    }
  }
  bf16* ob = out + (size_t)b * Obs
           + (size_t)(blockIdx.x * 64 + wave * 16 + kq * 4) * ldo + blockIdx.y * 64;
  #pragma unroll
  for (int ct = 0; ct < 4; ++ct)
    #pragma unroll
    for (int rr = 0; rr < 4; ++rr)
      ob[(size_t)rr * ldo + ct * 16 + r] = __float2bfloat16(acc[ct][rr]);
}

// -------- fused attention: S = Q*K^T (no-max softmax), O = P*V / rowsum --------
// R0's phase structure EXACTLY (4 waves, m-tile 64, reg-staged K, V direct
// gathers, 2 barriers/iter, identical per-phase liveness) with the n-tile
// halved to 32 rows -> grid (8, 98): 98 blocks/XCD instead of 49, so ALL 32
// CUs of each XCD carry 2 resident blocks from t=0 (was 17x2 + 15x1 -> the
// 2-block CUs set a ~2x makespan while 15 CUs half-idled). Wave w: QK rows
// (w&1)*16, cols (w>>1)*32 (sa[2], qf unchanged 48 VGPR); PV d-cols
// [w*96,+96) unchanged. Registers strictly below R0 (acc 96->48, sa 16->8).
__global__ __launch_bounds__(256, 2) void kattn(const bf16* __restrict__ Qb,
                                                const bf16* __restrict__ Kb,
                                                const bf16* __restrict__ Vt,
                                                float* __restrict__ out) {
  __shared__ __align__(16) bf16 Kl[64][DIM + 8];   // 50176 B
  __shared__ __align__(16) bf16 Pl[2][16][68];     //  4352 B (stride 34 dw, odd/2)
  __shared__ float rsum2[2][32];                   //   256 B  (total 54784 B)

  int b = blockIdx.x;
  int n0 = blockIdx.y * 32;
  int tid = threadIdx.x;
  int wave = tid >> 6, lane = tid & 63;
  int r = lane & 15, kq = lane >> 4;
  int rw = wave & 1;    // row group: 16 of the 32 n-rows (QK)
  int cw = wave >> 1;   // col group: 32 of the 64 m-cols (QK)

  // Q fragments for this wave's 16 rows, full K=384 (12 k-steps)
  short8 qf[12];
  {
    const bf16* qp = Qb + ((size_t)b * SEQ + n0 + rw * 16 + r) * DIM + kq * 8;
    #pragma unroll
    for (int ks = 0; ks < 12; ++ks) qf[ks] = *(const short8*)(qp + ks * 32);
  }
  fx4 zero = {0.f, 0.f, 0.f, 0.f};
  fx4 acc[2][6];
  #pragma unroll
  for (int i = 0; i < 2; ++i)
    #pragma unroll
    for (int j = 0; j < 6; ++j) acc[i][j] = zero;
  float rs[4] = {0.f, 0.f, 0.f, 0.f};
  const float cexp = 0.07362223f;   // log2(e)/sqrt(384): exp(s*scale) = exp2(s*cexp)

  const bf16* kbase = Kb + (size_t)b * SEQ * DIM;
  const bf16* vbase = Vt + (size_t)b * DIM * SEQ;

  // staging geometry (per thread): one K row quarter
  int srow = tid >> 2, scb = (tid & 3) * 96;

  for (int im = 0; im < SEQ / 64; ++im) {
    int m0 = im * 64;
    { // stage K tile: 64 rows x 384 bf16 (reg-staged)
      const i4* g = (const i4*)(kbase + (size_t)(m0 + srow) * DIM + scb);
      i4* l = (i4*)(&Kl[srow][scb]);
      #pragma unroll
      for (int p = 0; p < 12; ++p) l[p] = g[p];
    }
    // V fragments direct from global (L2): latency hides under QK
    short8 vf[2][6];
    #pragma unroll
    for (int ks2 = 0; ks2 < 2; ++ks2)
      #pragma unroll
      for (int dtl = 0; dtl < 6; ++dtl) {
        int d = (wave * 6 + dtl) * 16 + r;
        vf[ks2][dtl] = *(const short8*)(vbase + (size_t)d * SEQ + m0 + ks2 * 32 + kq * 8);
      }
    __syncthreads();   // A: Kl ready; also all waves done PV(im-1) -> Pl free
    // S = Q * K^T : wave's 16 rows x 32 cols
    fx4 sa[2] = {zero, zero};
    #pragma unroll
    for (int ks = 0; ks < 12; ++ks) {
      #pragma unroll
      for (int ct = 0; ct < 2; ++ct) {
        short8 bfr = *(const short8*)(&Kl[cw * 32 + ct * 16 + r][ks * 32 + kq * 8]);
        sa[ct] = MFMA(qf[ks], bfr, sa[ct]);
      }
    }
    // exp (no max subtraction), partial rowsum (per-lane, reduce deferred), P -> LDS
    #pragma unroll
    for (int rr = 0; rr < 4; ++rr) {
      float e0 = exp2f(sa[0][rr] * cexp);
      float e1 = exp2f(sa[1][rr] * cexp);
      int row = kq * 4 + rr;
      Pl[rw][row][cw * 32 + r]      = __float2bfloat16(e0);
      Pl[rw][row][cw * 32 + 16 + r] = __float2bfloat16(e1);
      rs[rr] += e0 + e1;
    }
    __syncthreads();   // B: Pl ready; also all waves done QK -> Kl free next iter
    // PV: O[rg*16+i][d] += P[rg*16+i][m] * V[m][d], wave's 96 d-cols
    #pragma unroll
    for (int ks2 = 0; ks2 < 2; ++ks2) {
      short8 pa[2];
      #pragma unroll
      for (int rg = 0; rg < 2; ++rg)
        pa[rg] = *(const short8*)(&Pl[rg][r][ks2 * 32 + kq * 8]);
      #pragma unroll
      for (int dtl = 0; dtl < 6; ++dtl) {
        #pragma unroll
        for (int rg = 0; rg < 2; ++rg)
          acc[rg][dtl] = MFMA(pa[rg], vf[ks2][dtl], acc[rg][dtl]);
      }
    }
  }
  // rowsum: reduce each wave's 32-col partial over the 16 r-lanes; the two
  // col-group waves sharing the same rows combine in the epilogue.
  #pragma unroll
  for (int rr = 0; rr < 4; ++rr) {
    float v = rs[rr];
    v += __shfl_xor(v, 1);
    v += __shfl_xor(v, 2);
    v += __shfl_xor(v, 4);
    v += __shfl_xor(v, 8);
    if (r == 0) rsum2[cw][rw * 16 + kq * 4 + rr] = v;
  }
  __syncthreads();
  // epilogue: divide and store transposed: out[b][d][n]
  float* ob = out + (size_t)b * DIM * SEQ;
  #pragma unroll
  for (int rg = 0; rg < 2; ++rg) {
    #pragma unroll
    for (int rr = 0; rr < 4; ++rr) {
      int row = rg * 16 + kq * 4 + rr;
      float inv = 1.0f / (rsum2[0][row] + rsum2[1][row]);
      int n = n0 + row;
      #pragma unroll
      for (int dtl = 0; dtl < 6; ++dtl) {
        int d = (wave * 6 + dtl) * 16 + r;
        ob[(size_t)d * SEQ + n] = acc[rg][dtl][rr] * inv;
      }
    }
  }
}

extern "C" void kernel_launch(void* const* d_in, const int* in_sizes, int n_in,
                              void* d_out, int out_size, void* d_ws, size_t ws_size,
                              hipStream_t stream) {
  const float* x  = (const float*)d_in[0];
  const float* w1 = (const float*)d_in[1];
  const float* w2 = (const float*)d_in[2];
  float* out = (float*)d_out;

  char* ws = (char*)d_ws;
  size_t SZ = (size_t)NBATCH * SEQ * DIM * sizeof(bf16);   // 19,267,584 B
  bf16* Kb  = (bf16*)(ws);                 // [B][N][C]
  bf16* Qb  = (bf16*)(ws + SZ);            // [B][N][C]
  bf16* Vt  = (bf16*)(ws + 2 * SZ);        // [B][C][N]
  bf16* w1b = (bf16*)(ws + 3 * SZ);
  bf16* w2b = (bf16*)(ws + 3 * SZ + (size_t)DIM * DIM * sizeof(bf16));

  // 1) transpose+convert x -> Kb
  ktrans<<<dim3(SEQ / 64, DIM / 64, NBATCH), 256, 0, stream>>>(x, Kb);
  // 2) weights -> bf16
  kwconv<<<dim3(DIM * DIM / 256), 256, 0, stream>>>(w1, w2, w1b, w2b);
  // 3) Q[b][n][d] = sum_c Kb[b][n][c] * w1[d][c]
  kgemm<<<dim3(SEQ / 64, DIM / 64, NBATCH), 256, 0, stream>>>(
      Kb, (long long)SEQ * DIM, w1b, 0LL, Qb, (long long)SEQ * DIM, DIM);
  // 4) Vt[b][d][m] = sum_c w2[d][c] * Kb[b][m][c]
  kgemm<<<dim3(DIM / 64, SEQ / 64, NBATCH), 256, 0, stream>>>(
      w2b, 0LL, Kb, (long long)SEQ * DIM, Vt, (long long)DIM * SEQ, SEQ);
  // 5) fused attention -> out[b][d][n]  (batch on blockIdx.x -> one XCD per batch)
  kattn<<<dim3(NBATCH, SEQ / 32), 256, 0, stream>>>(Qb, Kb, Vt, out);
}

// Round 9
// 273.529 us; speedup vs baseline: 1.7839x; 1.7839x over previous
//
#include <hip/hip_runtime.h>
#include <hip/hip_bf16.h>

#define DIM 384
#define SEQ 3136   // 56*56
#define NBATCH 8

typedef __attribute__((ext_vector_type(8))) short short8;  // 8 x bf16 (4 VGPRs)
typedef __attribute__((ext_vector_type(4))) float fx4;
typedef __attribute__((ext_vector_type(4))) int i4;
typedef __hip_bfloat16 bf16;

#define MFMA(a,b,c) __builtin_amdgcn_mfma_f32_16x16x32_bf16(a,b,c,0,0,0)

// -------- fused: x[b][c][n] f32 -> kb[b][n][c] bf16 (z<8), weights->bf16 (z==8) --------
__global__ __launch_bounds__(256) void ktransw(const float* __restrict__ x,
                                               bf16* __restrict__ kb,
                                               const float* __restrict__ w1,
                                               const float* __restrict__ w2,
                                               bf16* __restrict__ w1b,
                                               bf16* __restrict__ w2b) {
  if (blockIdx.z == 8) {   // weight conversion slice: 294 blocks x 512 elems
    int id = blockIdx.y * 49 + blockIdx.x;
    int i0 = id * 512 + threadIdx.x;
    if (i0 < DIM * DIM) { w1b[i0] = __float2bfloat16(w1[i0]); w2b[i0] = __float2bfloat16(w2[i0]); }
    int i1 = i0 + 256;
    if (i1 < DIM * DIM) { w1b[i1] = __float2bfloat16(w1[i1]); w2b[i1] = __float2bfloat16(w2[i1]); }
    return;
  }
  __shared__ float t[64][65];
  int b = blockIdx.z;
  int n0 = blockIdx.x * 64, c0 = blockIdx.y * 64;
  int tid = threadIdx.x;
  {
    int nl = tid & 63, cl = tid >> 6;
    const float* xp = x + ((size_t)b * DIM + c0) * SEQ + n0;
    #pragma unroll
    for (int p = 0; p < 16; ++p) {
      int c = cl * 16 + p;
      t[c][nl] = xp[(size_t)c * SEQ + nl];
    }
  }
  __syncthreads();
  {
    int cc = tid & 63, nr = tid >> 6;
    bf16* kp = kb + ((size_t)b * SEQ + n0) * DIM + c0;
    #pragma unroll
    for (int p = 0; p < 16; ++p) {
      int n = nr * 16 + p;
      kp[(size_t)n * DIM + cc] = __float2bfloat16(t[cc][n]);
    }
  }
}

// -------- fused dual GEMM: out[r][c] = sum_k A[r][k] * Bt[c][k]  (K=384) --------
// z<8:  Q[b][n][d] = Kb[b][n][:] . w1b[d][:]   (b = z)
// z>=8: Vt[b][d][m] = w2b[d][:] . Kb[b][m][:]  (b = z-8)
// Independent outputs; one dispatch removes an inter-kernel gap and overlaps
// tails; both slices read Kb -> L2 co-residency. Inner body = R7 kgemm
// (two 192-wide K-steps, LDS 51,200 B -> 3 blocks/CU; R7-proven).
__global__ __launch_bounds__(256, 3) void kgemm2(const bf16* __restrict__ Kb,
                                                 const bf16* __restrict__ w1b,
                                                 const bf16* __restrict__ w2b,
                                                 bf16* __restrict__ Qb,
                                                 bf16* __restrict__ Vt) {
  __shared__ __align__(16) bf16 At[64][200];
  __shared__ __align__(16) bf16 Bs[64][200];
  int z = blockIdx.z, id = blockIdx.x;
  const bf16 *A, *Bt;
  bf16* out;
  long long Abs, Bbs, Obs;
  int ldo, bx, by, b;
  if (z < 8) {
    b = z; A = Kb; Abs = (long long)SEQ * DIM; Bt = w1b; Bbs = 0;
    out = Qb; Obs = (long long)SEQ * DIM; ldo = DIM;
    bx = id % 49; by = id / 49;              // 49 x 6
  } else {
    b = z - 8; A = w2b; Abs = 0; Bt = Kb; Bbs = (long long)SEQ * DIM;
    out = Vt; Obs = (long long)DIM * SEQ; ldo = SEQ;
    bx = id % 6; by = id / 6;                // 6 x 49
  }
  int tid = threadIdx.x;
  const bf16* Ab = A + (size_t)b * Abs + (size_t)bx * 64 * DIM;
  const bf16* Bb = Bt + (size_t)b * Bbs + (size_t)by * 64 * DIM;
  int row = tid >> 2, cb = (tid & 3) * 48;
  int wave = tid >> 6, lane = tid & 63;
  int r = lane & 15, kq = lane >> 4;
  fx4 zero = {0.f, 0.f, 0.f, 0.f};
  fx4 acc[4];
  #pragma unroll
  for (int i = 0; i < 4; ++i) acc[i] = zero;
  #pragma unroll
  for (int kb2 = 0; kb2 < DIM; kb2 += 192) {
    if (kb2) __syncthreads();   // all waves done reading previous K-step tiles
    {
      const i4* ga = (const i4*)(Ab + (size_t)row * DIM + kb2 + cb);
      const i4* gb = (const i4*)(Bb + (size_t)row * DIM + kb2 + cb);
      i4* la = (i4*)(&At[row][cb]);
      i4* lb = (i4*)(&Bs[row][cb]);
      #pragma unroll
      for (int p = 0; p < 6; ++p) { la[p] = ga[p]; lb[p] = gb[p]; }
    }
    __syncthreads();
    #pragma unroll
    for (int ks = 0; ks < 6; ++ks) {
      short8 af = *(const short8*)(&At[wave * 16 + r][ks * 32 + kq * 8]);
      #pragma unroll
      for (int ct = 0; ct < 4; ++ct) {
        short8 bfr = *(const short8*)(&Bs[ct * 16 + r][ks * 32 + kq * 8]);
        acc[ct] = MFMA(af, bfr, acc[ct]);
      }
    }
  }
  bf16* ob = out + (size_t)b * Obs
           + (size_t)(bx * 64 + wave * 16 + kq * 4) * ldo + by * 64;
  #pragma unroll
  for (int ct = 0; ct < 4; ++ct)
    #pragma unroll
    for (int rr = 0; rr < 4; ++rr)
      ob[(size_t)rr * ldo + ct * 16 + r] = __float2bfloat16(acc[ct][rr]);
}

// -------- fused attention: S = Q*K^T (no-max softmax), O = P*V / rowsum --------
// EXACT round-0 kernel (measured 242 us kattn, five times): grid (8, 49),
// 4 waves, m-tile 64, K staged in LDS (reg-staged), V direct global gathers,
// 2 barriers per m-iter. Seven restructuring attempts (occupancy, read-halving,
// DMA staging, V prefetch schedules, n-tile halving) all regressed -- each
// tripped the 128-arch-VGPR boundary, added serialization, or broke K-tile
// amortization / L2 residency. Do not modify phase structure or liveness.
__global__ __launch_bounds__(256, 2) void kattn(const bf16* __restrict__ Qb,
                                                const bf16* __restrict__ Kb,
                                                const bf16* __restrict__ Vt,
                                                float* __restrict__ out) {
  __shared__ __align__(16) bf16 Kl[64][DIM + 8];   // 50176 B
  __shared__ __align__(16) bf16 Pl[4][16][68];     //  8704 B (stride 34 dw, odd/2)
  __shared__ float rsum[64];

  int b = blockIdx.x;
  int n0 = blockIdx.y * 64;
  int tid = threadIdx.x;
  int wave = tid >> 6, lane = tid & 63;
  int r = lane & 15, kq = lane >> 4;

  // Q fragments for this wave's 16 rows, full K=384 (12 k-steps)
  short8 qf[12];
  {
    const bf16* qp = Qb + ((size_t)b * SEQ + n0 + wave * 16 + r) * DIM + kq * 8;
    #pragma unroll
    for (int ks = 0; ks < 12; ++ks) qf[ks] = *(const short8*)(qp + ks * 32);
  }
  fx4 zero = {0.f, 0.f, 0.f, 0.f};
  fx4 acc[4][6];
  #pragma unroll
  for (int i = 0; i < 4; ++i)
    #pragma unroll
    for (int j = 0; j < 6; ++j) acc[i][j] = zero;
  float rs[4] = {0.f, 0.f, 0.f, 0.f};
  const float cexp = 0.07362223f;   // log2(e)/sqrt(384): exp(s*scale) = exp2(s*cexp)

  const bf16* kbase = Kb + (size_t)b * SEQ * DIM;
  const bf16* vbase = Vt + (size_t)b * DIM * SEQ;

  // staging geometry (per thread): one K row quarter
  int srow = tid >> 2, scb = (tid & 3) * 96;

  for (int im = 0; im < SEQ / 64; ++im) {
    int m0 = im * 64;
    { // stage K tile: 64 rows x 384 bf16 (reg-staged)
      const i4* g = (const i4*)(kbase + (size_t)(m0 + srow) * DIM + scb);
      i4* l = (i4*)(&Kl[srow][scb]);
      #pragma unroll
      for (int p = 0; p < 12; ++p) l[p] = g[p];
    }
    // V fragments direct from global (L2): latency hides under QK
    short8 vf[2][6];
    #pragma unroll
    for (int ks2 = 0; ks2 < 2; ++ks2)
      #pragma unroll
      for (int dtl = 0; dtl < 6; ++dtl) {
        int d = (wave * 6 + dtl) * 16 + r;
        vf[ks2][dtl] = *(const short8*)(vbase + (size_t)d * SEQ + m0 + ks2 * 32 + kq * 8);
      }
    __syncthreads();   // A: Kl ready; also all waves done PV(im-1) -> Pl free
    // S = Q * K^T : wave's 16 rows x 64 cols
    fx4 sa[4];
    #pragma unroll
    for (int ct = 0; ct < 4; ++ct) sa[ct] = zero;
    #pragma unroll
    for (int ks = 0; ks < 12; ++ks) {
      #pragma unroll
      for (int ct = 0; ct < 4; ++ct) {
        short8 bfr = *(const short8*)(&Kl[ct * 16 + r][ks * 32 + kq * 8]);
        sa[ct] = MFMA(qf[ks], bfr, sa[ct]);
      }
    }
    // exp (no max subtraction), partial rowsum (per-lane, reduce deferred), P -> LDS
    #pragma unroll
    for (int rr = 0; rr < 4; ++rr) {
      float e0 = exp2f(sa[0][rr] * cexp);
      float e1 = exp2f(sa[1][rr] * cexp);
      float e2 = exp2f(sa[2][rr] * cexp);
      float e3 = exp2f(sa[3][rr] * cexp);
      int row = kq * 4 + rr;
      Pl[wave][row][r]      = __float2bfloat16(e0);
      Pl[wave][row][16 + r] = __float2bfloat16(e1);
      Pl[wave][row][32 + r] = __float2bfloat16(e2);
      Pl[wave][row][48 + r] = __float2bfloat16(e3);
      rs[rr] += (e0 + e1) + (e2 + e3);
    }
    __syncthreads();   // B: Pl ready; also all waves done QK -> Kl free next iter
    // PV: O[rg*16+i][d] += P[rg*16+i][m] * V[m][d], wave's 96 d-cols
    #pragma unroll
    for (int ks2 = 0; ks2 < 2; ++ks2) {
      short8 pa[4];
      #pragma unroll
      for (int rg = 0; rg < 4; ++rg)
        pa[rg] = *(const short8*)(&Pl[rg][r][ks2 * 32 + kq * 8]);
      #pragma unroll
      for (int dtl = 0; dtl < 6; ++dtl) {
        #pragma unroll
        for (int rg = 0; rg < 4; ++rg)
          acc[rg][dtl] = MFMA(pa[rg], vf[ks2][dtl], acc[rg][dtl]);
      }
    }
  }
  // final rowsum reduce over the 16 r-lanes (cols partition), share across waves
  #pragma unroll
  for (int rr = 0; rr < 4; ++rr) {
    float v = rs[rr];
    v += __shfl_xor(v, 1);
    v += __shfl_xor(v, 2);
    v += __shfl_xor(v, 4);
    v += __shfl_xor(v, 8);
    if (r == 0) rsum[wave * 16 + kq * 4 + rr] = v;
  }
  __syncthreads();
  // epilogue: divide and store transposed: out[b][d][n]
  float* ob = out + (size_t)b * DIM * SEQ;
  #pragma unroll
  for (int rg = 0; rg < 4; ++rg) {
    #pragma unroll
    for (int rr = 0; rr < 4; ++rr) {
      float inv = 1.0f / rsum[rg * 16 + kq * 4 + rr];
      int n = n0 + rg * 16 + kq * 4 + rr;
      #pragma unroll
      for (int dtl = 0; dtl < 6; ++dtl) {
        int d = (wave * 6 + dtl) * 16 + r;
        ob[(size_t)d * SEQ + n] = acc[rg][dtl][rr] * inv;
      }
    }
  }
}

extern "C" void kernel_launch(void* const* d_in, const int* in_sizes, int n_in,
                              void* d_out, int out_size, void* d_ws, size_t ws_size,
                              hipStream_t stream) {
  const float* x  = (const float*)d_in[0];
  const float* w1 = (const float*)d_in[1];
  const float* w2 = (const float*)d_in[2];
  float* out = (float*)d_out;

  char* ws = (char*)d_ws;
  size_t SZ = (size_t)NBATCH * SEQ * DIM * sizeof(bf16);   // 19,267,584 B
  bf16* Kb  = (bf16*)(ws);                 // [B][N][C]
  bf16* Qb  = (bf16*)(ws + SZ);            // [B][N][C]
  bf16* Vt  = (bf16*)(ws + 2 * SZ);        // [B][C][N]
  bf16* w1b = (bf16*)(ws + 3 * SZ);
  bf16* w2b = (bf16*)(ws + 3 * SZ + (size_t)DIM * DIM * sizeof(bf16));

  // 1) transpose+convert x -> Kb; weights -> bf16 (fused, z==8 slice)
  ktransw<<<dim3(SEQ / 64, DIM / 64, NBATCH + 1), 256, 0, stream>>>(
      x, Kb, w1, w2, w1b, w2b);
  // 2) fused dual GEMM: z<8 -> Qb, z>=8 -> Vt
  kgemm2<<<dim3(294, 1, 2 * NBATCH), 256, 0, stream>>>(Kb, w1b, w2b, Qb, Vt);
  // 3) fused attention -> out[b][d][n]  (batch on blockIdx.x -> one XCD per batch)
  kattn<<<dim3(NBATCH, SEQ / 64), 256, 0, stream>>>(Qb, Kb, Vt, out);
}

// Round 10
// 266.336 us; speedup vs baseline: 1.8321x; 1.0270x over previous
//
#include <hip/hip_runtime.h>
#include <hip/hip_bf16.h>

#define DIM 384
#define SEQ 3136   // 56*56
#define NBATCH 8

typedef __attribute__((ext_vector_type(8))) short short8;  // 8 x bf16 (4 VGPRs)
typedef __attribute__((ext_vector_type(4))) float fx4;
typedef __attribute__((ext_vector_type(4))) int i4;
typedef __hip_bfloat16 bf16;

#define MFMA(a,b,c) __builtin_amdgcn_mfma_f32_16x16x32_bf16(a,b,c,0,0,0)

// -------- fused: x[b][c][n] f32 -> kb[b][n][c] bf16 (z<8), weights->bf16 (z==8) --------
__global__ __launch_bounds__(256) void ktransw(const float* __restrict__ x,
                                               bf16* __restrict__ kb,
                                               const float* __restrict__ w1,
                                               const float* __restrict__ w2,
                                               bf16* __restrict__ w1b,
                                               bf16* __restrict__ w2b) {
  if (blockIdx.z == 8) {   // weight conversion slice: 294 blocks x 512 elems
    int id = blockIdx.y * 49 + blockIdx.x;
    int i0 = id * 512 + threadIdx.x;
    if (i0 < DIM * DIM) { w1b[i0] = __float2bfloat16(w1[i0]); w2b[i0] = __float2bfloat16(w2[i0]); }
    int i1 = i0 + 256;
    if (i1 < DIM * DIM) { w1b[i1] = __float2bfloat16(w1[i1]); w2b[i1] = __float2bfloat16(w2[i1]); }
    return;
  }
  __shared__ float t[64][65];
  int b = blockIdx.z;
  int n0 = blockIdx.x * 64, c0 = blockIdx.y * 64;
  int tid = threadIdx.x;
  {
    int nl = tid & 63, cl = tid >> 6;
    const float* xp = x + ((size_t)b * DIM + c0) * SEQ + n0;
    #pragma unroll
    for (int p = 0; p < 16; ++p) {
      int c = cl * 16 + p;
      t[c][nl] = xp[(size_t)c * SEQ + nl];
    }
  }
  __syncthreads();
  {
    // paired stores: each lane writes 2 consecutive c as one bfloat162 (4B)
    int cp = (tid & 31) * 2, nr = tid >> 5;   // 32 col-pairs x 8 row-groups
    bf16* kp = kb + ((size_t)b * SEQ + n0) * DIM + c0;
    #pragma unroll
    for (int p = 0; p < 8; ++p) {
      int n = nr * 8 + p;
      __hip_bfloat162 v;
      v.x = __float2bfloat16(t[cp][n]);
      v.y = __float2bfloat16(t[cp + 1][n]);
      *reinterpret_cast<__hip_bfloat162*>(&kp[(size_t)n * DIM + cp]) = v;
    }
  }
}

// -------- fused dual GEMM: out[r][c] = sum_k A[r][k] * Bt[c][k]  (K=384) --------
// z<8:  Q[b][n][d] = Kb[b][n][:] . w1b[d][:]   (b = z)
// z>=8: Vt[b][d][m] = w2b[d][:] . Kb[b][m][:]  (b = z-8)
// Inner body = R7 kgemm (two 192-wide K-steps, LDS 51,200 B -> 3 blocks/CU).
// s_setprio(1) around the MFMA cluster: 3 desynced blocks/CU -> favor the
// MFMA-phase wave over other blocks' staging waves (T5).
__global__ __launch_bounds__(256, 3) void kgemm2(const bf16* __restrict__ Kb,
                                                 const bf16* __restrict__ w1b,
                                                 const bf16* __restrict__ w2b,
                                                 bf16* __restrict__ Qb,
                                                 bf16* __restrict__ Vt) {
  __shared__ __align__(16) bf16 At[64][200];
  __shared__ __align__(16) bf16 Bs[64][200];
  int z = blockIdx.z, id = blockIdx.x;
  const bf16 *A, *Bt;
  bf16* out;
  long long Abs, Bbs, Obs;
  int ldo, bx, by, b;
  if (z < 8) {
    b = z; A = Kb; Abs = (long long)SEQ * DIM; Bt = w1b; Bbs = 0;
    out = Qb; Obs = (long long)SEQ * DIM; ldo = DIM;
    bx = id % 49; by = id / 49;              // 49 x 6
  } else {
    b = z - 8; A = w2b; Abs = 0; Bt = Kb; Bbs = (long long)SEQ * DIM;
    out = Vt; Obs = (long long)DIM * SEQ; ldo = SEQ;
    bx = id % 6; by = id / 6;                // 6 x 49
  }
  int tid = threadIdx.x;
  const bf16* Ab = A + (size_t)b * Abs + (size_t)bx * 64 * DIM;
  const bf16* Bb = Bt + (size_t)b * Bbs + (size_t)by * 64 * DIM;
  int row = tid >> 2, cb = (tid & 3) * 48;
  int wave = tid >> 6, lane = tid & 63;
  int r = lane & 15, kq = lane >> 4;
  fx4 zero = {0.f, 0.f, 0.f, 0.f};
  fx4 acc[4];
  #pragma unroll
  for (int i = 0; i < 4; ++i) acc[i] = zero;
  #pragma unroll
  for (int kb2 = 0; kb2 < DIM; kb2 += 192) {
    if (kb2) __syncthreads();   // all waves done reading previous K-step tiles
    {
      const i4* ga = (const i4*)(Ab + (size_t)row * DIM + kb2 + cb);
      const i4* gb = (const i4*)(Bb + (size_t)row * DIM + kb2 + cb);
      i4* la = (i4*)(&At[row][cb]);
      i4* lb = (i4*)(&Bs[row][cb]);
      #pragma unroll
      for (int p = 0; p < 6; ++p) { la[p] = ga[p]; lb[p] = gb[p]; }
    }
    __syncthreads();
    __builtin_amdgcn_s_setprio(1);
    #pragma unroll
    for (int ks = 0; ks < 6; ++ks) {
      short8 af = *(const short8*)(&At[wave * 16 + r][ks * 32 + kq * 8]);
      #pragma unroll
      for (int ct = 0; ct < 4; ++ct) {
        short8 bfr = *(const short8*)(&Bs[ct * 16 + r][ks * 32 + kq * 8]);
        acc[ct] = MFMA(af, bfr, acc[ct]);
      }
    }
    __builtin_amdgcn_s_setprio(0);
  }
  bf16* ob = out + (size_t)b * Obs
           + (size_t)(bx * 64 + wave * 16 + kq * 4) * ldo + by * 64;
  #pragma unroll
  for (int ct = 0; ct < 4; ++ct)
    #pragma unroll
    for (int rr = 0; rr < 4; ++rr)
      ob[(size_t)rr * ldo + ct * 16 + r] = __float2bfloat16(acc[ct][rr]);
}

// -------- fused attention: S = Q*K^T (no-max softmax), O = P*V / rowsum --------
// EXACT round-0 structure (measured 242 us kattn, six dispatدر sets): grid (8,49),
// 4 waves, m-tile 64, K staged in LDS (reg-staged), V direct global gathers,
// 2 barriers per m-iter. Seven restructures all regressed (128+128 v+a budget
// at 8 waves/CU is exactly saturated; K-amortization and 2-block drain hiding
// are both required). ONLY addition vs R0: s_setprio(1) around the two MFMA
// clusters -- the 2 co-resident blocks/CU run desynced, so the hint arbitrates
// the SIMD toward MFMA-phase waves (T5: +4-7% on desynced attn, m191).
__global__ __launch_bounds__(256, 2) void kattn(const bf16* __restrict__ Qb,
                                                const bf16* __restrict__ Kb,
                                                const bf16* __restrict__ Vt,
                                                float* __restrict__ out) {
  __shared__ __align__(16) bf16 Kl[64][DIM + 8];   // 50176 B
  __shared__ __align__(16) bf16 Pl[4][16][68];     //  8704 B (stride 34 dw, odd/2)
  __shared__ float rsum[64];

  int b = blockIdx.x;
  int n0 = blockIdx.y * 64;
  int tid = threadIdx.x;
  int wave = tid >> 6, lane = tid & 63;
  int r = lane & 15, kq = lane >> 4;

  // Q fragments for this wave's 16 rows, full K=384 (12 k-steps)
  short8 qf[12];
  {
    const bf16* qp = Qb + ((size_t)b * SEQ + n0 + wave * 16 + r) * DIM + kq * 8;
    #pragma unroll
    for (int ks = 0; ks < 12; ++ks) qf[ks] = *(const short8*)(qp + ks * 32);
  }
  fx4 zero = {0.f, 0.f, 0.f, 0.f};
  fx4 acc[4][6];
  #pragma unroll
  for (int i = 0; i < 4; ++i)
    #pragma unroll
    for (int j = 0; j < 6; ++j) acc[i][j] = zero;
  float rs[4] = {0.f, 0.f, 0.f, 0.f};
  const float cexp = 0.07362223f;   // log2(e)/sqrt(384): exp(s*scale) = exp2(s*cexp)

  const bf16* kbase = Kb + (size_t)b * SEQ * DIM;
  const bf16* vbase = Vt + (size_t)b * DIM * SEQ;

  // staging geometry (per thread): one K row quarter
  int srow = tid >> 2, scb = (tid & 3) * 96;

  for (int im = 0; im < SEQ / 64; ++im) {
    int m0 = im * 64;
    { // stage K tile: 64 rows x 384 bf16 (reg-staged)
      const i4* g = (const i4*)(kbase + (size_t)(m0 + srow) * DIM + scb);
      i4* l = (i4*)(&Kl[srow][scb]);
      #pragma unroll
      for (int p = 0; p < 12; ++p) l[p] = g[p];
    }
    // V fragments direct from global (L2): latency hides under QK
    short8 vf[2][6];
    #pragma unroll
    for (int ks2 = 0; ks2 < 2; ++ks2)
      #pragma unroll
      for (int dtl = 0; dtl < 6; ++dtl) {
        int d = (wave * 6 + dtl) * 16 + r;
        vf[ks2][dtl] = *(const short8*)(vbase + (size_t)d * SEQ + m0 + ks2 * 32 + kq * 8);
      }
    __syncthreads();   // A: Kl ready; also all waves done PV(im-1) -> Pl free
    // S = Q * K^T : wave's 16 rows x 64 cols
    fx4 sa[4];
    #pragma unroll
    for (int ct = 0; ct < 4; ++ct) sa[ct] = zero;
    __builtin_amdgcn_s_setprio(1);
    #pragma unroll
    for (int ks = 0; ks < 12; ++ks) {
      #pragma unroll
      for (int ct = 0; ct < 4; ++ct) {
        short8 bfr = *(const short8*)(&Kl[ct * 16 + r][ks * 32 + kq * 8]);
        sa[ct] = MFMA(qf[ks], bfr, sa[ct]);
      }
    }
    __builtin_amdgcn_s_setprio(0);
    // exp (no max subtraction), partial rowsum (per-lane, reduce deferred), P -> LDS
    #pragma unroll
    for (int rr = 0; rr < 4; ++rr) {
      float e0 = exp2f(sa[0][rr] * cexp);
      float e1 = exp2f(sa[1][rr] * cexp);
      float e2 = exp2f(sa[2][rr] * cexp);
      float e3 = exp2f(sa[3][rr] * cexp);
      int row = kq * 4 + rr;
      Pl[wave][row][r]      = __float2bfloat16(e0);
      Pl[wave][row][16 + r] = __float2bfloat16(e1);
      Pl[wave][row][32 + r] = __float2bfloat16(e2);
      Pl[wave][row][48 + r] = __float2bfloat16(e3);
      rs[rr] += (e0 + e1) + (e2 + e3);
    }
    __syncthreads();   // B: Pl ready; also all waves done QK -> Kl free next iter
    // PV: O[rg*16+i][d] += P[rg*16+i][m] * V[m][d], wave's 96 d-cols
    __builtin_amdgcn_s_setprio(1);
    #pragma unroll
    for (int ks2 = 0; ks2 < 2; ++ks2) {
      short8 pa[4];
      #pragma unroll
      for (int rg = 0; rg < 4; ++rg)
        pa[rg] = *(const short8*)(&Pl[rg][r][ks2 * 32 + kq * 8]);
      #pragma unroll
      for (int dtl = 0; dtl < 6; ++dtl) {
        #pragma unroll
        for (int rg = 0; rg < 4; ++rg)
          acc[rg][dtl] = MFMA(pa[rg], vf[ks2][dtl], acc[rg][dtl]);
      }
    }
    __builtin_amdgcn_s_setprio(0);
  }
  // final rowsum reduce over the 16 r-lanes (cols partition), share across waves
  #pragma unroll
  for (int rr = 0; rr < 4; ++rr) {
    float v = rs[rr];
    v += __shfl_xor(v, 1);
    v += __shfl_xor(v, 2);
    v += __shfl_xor(v, 4);
    v += __shfl_xor(v, 8);
    if (r == 0) rsum[wave * 16 + kq * 4 + rr] = v;
  }
  __syncthreads();
  // epilogue: divide and store transposed: out[b][d][n]
  float* ob = out + (size_t)b * DIM * SEQ;
  #pragma unroll
  for (int rg = 0; rg < 4; ++rg) {
    #pragma unroll
    for (int rr = 0; rr < 4; ++rr) {
      float inv = 1.0f / rsum[rg * 16 + kq * 4 + rr];
      int n = n0 + rg * 16 + kq * 4 + rr;
      #pragma unroll
      for (int dtl = 0; dtl < 6; ++dtl) {
        int d = (wave * 6 + dtl) * 16 + r;
        ob[(size_t)d * SEQ + n] = acc[rg][dtl][rr] * inv;
      }
    }
  }
}

extern "C" void kernel_launch(void* const* d_in, const int* in_sizes, int n_in,
                              void* d_out, int out_size, void* d_ws, size_t ws_size,
                              hipStream_t stream) {
  const float* x  = (const float*)d_in[0];
  const float* w1 = (const float*)d_in[1];
  const float* w2 = (const float*)d_in[2];
  float* out = (float*)d_out;

  char* ws = (char*)d_ws;
  size_t SZ = (size_t)NBATCH * SEQ * DIM * sizeof(bf16);   // 19,267,584 B
  bf16* Kb  = (bf16*)(ws);                 // [B][N][C]
  bf16* Qb  = (bf16*)(ws + SZ);            // [B][N][C]
  bf16* Vt  = (bf16*)(ws + 2 * SZ);        // [B][C][N]
  bf16* w1b = (bf16*)(ws + 3 * SZ);
  bf16* w2b = (bf16*)(ws + 3 * SZ + (size_t)DIM * DIM * sizeof(bf16));

  // 1) transpose+convert x -> Kb; weights -> bf16 (fused, z==8 slice)
  ktransw<<<dim3(SEQ / 64, DIM / 64, NBATCH + 1), 256, 0, stream>>>(
      x, Kb, w1, w2, w1b, w2b);
  // 2) fused dual GEMM: z<8 -> Qb, z>=8 -> Vt
  kgemm2<<<dim3(294, 1, 2 * NBATCH), 256, 0, stream>>>(Kb, w1b, w2b, Qb, Vt);
  // 3) fused attention -> out[b][d][n]  (batch on blockIdx.x -> one XCD per batch)
  kattn<<<dim3(NBATCH, SEQ / 64), 256, 0, stream>>>(Qb, Kb, Vt, out);
}